// Round 12
// baseline (108.134 us; speedup 1.0000x reference)
//
#include <hip/hip_runtime.h>

#define ALG_DIM 248
#define ROWS 32                    // rows per main-kernel block
#define KSPLIT 4
#define KPB 62                     // k-slots per block (248/4)
#define CAP 256                    // uint2 capacity per bucket (pow2; max bucket ~160)
#define CNT_STRIDE 16              // ints between cnt entries (64 B -> spread L2 lines)
#define PLSTRIDE_B 3984            // plane stride bytes (248*16 + 16; /4 = 996 ≡ 4 mod 32)
#define PLSTRIDE_DW 996

typedef __fp16 h2v __attribute__((ext_vector_type(2)));
union H2U { unsigned u; h2v h; };

// ---------- scatter: flat, global-atomic cursors (round-1 verified form) ----
// cnt (16 KB) is zeroed by the preceding memset node. packed needs NO
// zero-init: k_main reads exactly [0, sz) per bucket (exact bounds), and
// all speculative reads (discarded prefetch, odd-tail .z/.w never used)
// stay inside the bucket's 128-uint4 workspace allocation.

__global__ void k_scatter(const int* __restrict__ idx_i, const int* __restrict__ idx_j,
                          const int* __restrict__ idx_k, const float* __restrict__ coeff,
                          int* __restrict__ cnt, uint2* __restrict__ packed, int nnz) {
    const int t = blockIdx.x * 256 + threadIdx.x;
    if (t >= nnz) return;
    const int k = idx_k[t];
    const int pos = atomicAdd(&cnt[k * CNT_STRIDE], 1);
    if (pos < CAP) {                           // structurally unreachable guard
        const float c = coeff[t];
        H2U hc; hc.h = __builtin_amdgcn_cvt_pkrtz(c, c);
        uint2 p;
        p.x = ((unsigned)idx_i[t] << 4) | ((unsigned)idx_j[t] << 20);
        p.y = hc.u;
        packed[((size_t)k << 8) + pos] = p;
    }
}

// ---------- main: plane-layout f16 gather, EXACT per-lane bounds ----------
// (verified 105.9 us in round 9 — best measured; 0 bank conflicts)
// 256 threads = 64 streams x 4 lanes over 32 rows x 62 slots. x,y in LDS as
// f16 in 4 planes: (col i, rows 8s..8s+7) at byte s*3984 + i*16. Lane q folds
// q*3984 into its base pointer once; gather = ds_read_b128 at base + i*16,
// bank window (i*4 + 4q) mod 32 sweeps all 32 banks as i varies.
// Gather loop runs to each lane's OWN bucket size (divergent; exec-masked
// lanes release the LDS pipe -> ~16% fewer LDS ops than wave-max padding)
// with an odd-triple tail guard. No zero-pad, no wave-max shuffle.

__global__ __launch_bounds__(256, 4) void k_main(
    const float* __restrict__ x, const float* __restrict__ y,
    const uint4* __restrict__ packed4,
    const int* __restrict__ cnt,
    const float* __restrict__ alpha_p, float* __restrict__ out)
{
    __shared__ __align__(16) unsigned xs32[4 * PLSTRIDE_DW];
    __shared__ __align__(16) unsigned ys32[4 * PLSTRIDE_DW];

    const int tid = threadIdx.x;
    const int r0  = blockIdx.x * ROWS;

    for (int u = tid; u < (ALG_DIM / 4) * (ROWS / 2); u += 256) {
        const int rp = u & 15;
        const int cq = u >> 4;
        const size_t ra = (size_t)(r0 + 2 * rp) * ALG_DIM + 4 * cq;
        const float4 xa = *reinterpret_cast<const float4*>(x + ra);
        const float4 xb = *reinterpret_cast<const float4*>(x + ra + ALG_DIM);
        const float4 ya = *reinterpret_cast<const float4*>(y + ra);
        const float4 yb = *reinterpret_cast<const float4*>(y + ra + ALG_DIM);
        const int pbase = (rp >> 2) * PLSTRIDE_DW + (rp & 3);
#define STG(d, XA, XB, YA, YB)                                                  \
        {                                                                       \
            const int dw = pbase + (4 * cq + (d)) * 4;                          \
            H2U hx; hx.h = __builtin_amdgcn_cvt_pkrtz(XA, XB);                  \
            H2U hy; hy.h = __builtin_amdgcn_cvt_pkrtz(YA, YB);                  \
            xs32[dw] = hx.u;                                                    \
            ys32[dw] = hy.u;                                                    \
        }
        STG(0, xa.x, xb.x, ya.x, yb.x)
        STG(1, xa.y, xb.y, ya.y, yb.y)
        STG(2, xa.z, xb.z, ya.z, yb.z)
        STG(3, xa.w, xb.w, ya.w, yb.w)
#undef STG
    }
    __syncthreads();

    const float alpha = alpha_p[0];
    const int   S     = tid >> 2;            // stream 0..63 (owns one slot)
    const int   q     = tid & 3;             // my plane (rows 8q..8q+7)

    const char* xsb = reinterpret_cast<const char*>(xs32) + q * PLSTRIDE_B;
    const char* ysb = reinterpret_cast<const char*>(ys32) + q * PLSTRIDE_B;

    if (S < KPB) {
        const int p  = blockIdx.y * KPB + S;
        const int k  = p;                    // identity (contiguous out columns)
        const int sz = min(cnt[p * CNT_STRIDE], CAP);
        const uint4* tp = packed4 + ((size_t)p << 7);   // 128 uint4 per bucket

        float a0 = 0.f, a1 = 0.f, a2 = 0.f, a3 = 0.f,
              a4 = 0.f, a5 = 0.f, a6 = 0.f, a7 = 0.f;

        const int nFull = sz >> 1;           // full uint4s (2 triples each)
        uint4 cur = tp[0];

#define PROC(PW, PC)                                                            \
        {                                                                       \
            const unsigned ox = (PW) & 0xFFFFu;                                 \
            const unsigned oy = (PW) >> 16;                                     \
            const uint4 wx = *reinterpret_cast<const uint4*>(xsb + ox);         \
            const uint4 wy = *reinterpret_cast<const uint4*>(ysb + oy);         \
            H2U cc; cc.u = (PC);                                                \
            H2U ux, uy;                                                         \
            ux.u = wx.x; uy.u = wy.x; c0 = (ux.h * uy.h) * cc.h + c0;           \
            ux.u = wx.y; uy.u = wy.y; c1 = (ux.h * uy.h) * cc.h + c1;           \
            ux.u = wx.z; uy.u = wy.z; c2 = (ux.h * uy.h) * cc.h + c2;           \
            ux.u = wx.w; uy.u = wy.w; c3 = (ux.h * uy.h) * cc.h + c3;           \
        }
#define FLUSH                                                                   \
        a0 += (float)c0.x; a1 += (float)c0.y;                                   \
        a2 += (float)c1.x; a3 += (float)c1.y;                                   \
        a4 += (float)c2.x; a5 += (float)c2.y;                                   \
        a6 += (float)c3.x; a7 += (float)c3.y;

        for (int chunk = 0; chunk < nFull; chunk += 16) {    // 32-triple window
            h2v c0 = (h2v)0.0f, c1 = (h2v)0.0f, c2 = (h2v)0.0f, c3 = (h2v)0.0f;
            const int hend = min(chunk + 16, nFull);
#pragma unroll 2
            for (int h = chunk; h < hend; ++h) {
                const uint4 nxt = tp[h + 1];  // prefetch; discarded at loop exit
                PROC(cur.x, cur.y)
                PROC(cur.z, cur.w)
                cur = nxt;
            }
            FLUSH
        }
        if (sz & 1) {                         // odd tail: cur == tp[nFull]
            h2v c0 = (h2v)0.0f, c1 = (h2v)0.0f, c2 = (h2v)0.0f, c3 = (h2v)0.0f;
            PROC(cur.x, cur.y)                // .z/.w of cur never touched
            FLUSH
        }
#undef FLUSH
#undef PROC

        const int rbase = r0 + (q << 3);
        out[(size_t)(rbase + 0) * ALG_DIM + k] = alpha * a0;
        out[(size_t)(rbase + 1) * ALG_DIM + k] = alpha * a1;
        out[(size_t)(rbase + 2) * ALG_DIM + k] = alpha * a2;
        out[(size_t)(rbase + 3) * ALG_DIM + k] = alpha * a3;
        out[(size_t)(rbase + 4) * ALG_DIM + k] = alpha * a4;
        out[(size_t)(rbase + 5) * ALG_DIM + k] = alpha * a5;
        out[(size_t)(rbase + 6) * ALG_DIM + k] = alpha * a6;
        out[(size_t)(rbase + 7) * ALG_DIM + k] = alpha * a7;
    }
}

// ---------- launch: 3 nodes (memset is 16 KB cnt only) ----------

extern "C" void kernel_launch(void* const* d_in, const int* in_sizes, int n_in,
                              void* d_out, int out_size, void* d_ws, size_t ws_size,
                              hipStream_t stream) {
    const float* x      = (const float*)d_in[0];
    const float* y      = (const float*)d_in[1];
    const int*   idx_i  = (const int*)d_in[2];
    const int*   idx_j  = (const int*)d_in[3];
    const int*   idx_k  = (const int*)d_in[4];
    const float* coeff  = (const float*)d_in[5];
    const float* alpha  = (const float*)d_in[6];
    float*       out    = (float*)d_out;

    const int nnz   = in_sizes[2];
    const int batch = in_sizes[0] / ALG_DIM;

    // ws: [cnt @0, 16 KB][packed @16384, 248*256*8 = 507904 B, no zero-init]
    char*  ws     = (char*)d_ws;
    int*   cnt    = (int*)ws;
    uint2* packed = (uint2*)(ws + 16384);

    hipMemsetAsync(ws, 0, 16384, stream);                   // cnt only

    k_scatter<<<(nnz + 255) / 256, 256, 0, stream>>>(idx_i, idx_j, idx_k, coeff,
                                                     cnt, packed, nnz);

    dim3 grid(batch / ROWS, KSPLIT);
    k_main<<<grid, 256, 0, stream>>>(x, y, (const uint4*)packed, cnt, alpha, out);
}